// Round 2
// baseline (1000.284 us; speedup 1.0000x reference)
//
#include <hip/hip_runtime.h>
#include <stdint.h>

#define HWP 2500
#define WID 50
#define CIN 1024
#define CB 256
#define COUT 1024

typedef __attribute__((ext_vector_type(8))) __bf16 bf16x8;
typedef __attribute__((ext_vector_type(4))) float f32x4;
typedef __attribute__((ext_vector_type(4))) float f4;
typedef __attribute__((ext_vector_type(8))) unsigned short u16x8;
typedef __attribute__((ext_vector_type(4))) unsigned short u16x4;
typedef unsigned short u16;

__device__ __forceinline__ u16 f2bf(float f) {
  union { float f; uint32_t u; } v; v.f = f;
  return (u16)((v.u + 0x7fffu + ((v.u >> 16) & 1u)) >> 16);
}

// ---------------- weight prep: fold scale, cast bf16, reorder w2 ----------------
// w1b: [256][1024]  (co-major, k=ci contiguous)
// w2r: [256][9*256] (k = (dy*3+dx)*256 + ci  -> each BK=64 stays in one offset)
// w3b: [1024][256]
__global__ __launch_bounds__(256) void prep_w(
    const float* __restrict__ w1, const float* __restrict__ w2,
    const float* __restrict__ w3, const float* __restrict__ s1,
    const float* __restrict__ s2, const float* __restrict__ s3,
    u16* __restrict__ w1b, u16* __restrict__ w2r, u16* __restrict__ w3b) {
  const int i = blockIdx.x * 256 + threadIdx.x;
  if (i < CB * CIN)  w1b[i] = f2bf(w1[i] * s1[i >> 10]);
  if (i < COUT * CB) w3b[i] = f2bf(w3[i] * s3[i >> 8]);
  if (i < CB * 2304) {
    const int co = i / 2304;
    const int k = i - co * 2304;
    const int off = k >> 8, ci = k & 255;
    w2r[i] = f2bf(w2[(co * CB + ci) * 9 + off] * s2[co]);
  }
}

// 4 waves; wave wid owns co rows [wid*64, wid*64+64); all waves share the 64-pixel B tile.
// acc[mf][nf]: mf = co 16-frag (4), nf = pixel 16-frag (4).
__device__ __forceinline__ void mfma_tile4(const u16 (&Asm)[256][72],
                                           const u16 (&Bsm)[64][72],
                                           f32x4 (&acc)[4][4], int lane, int wid) {
#pragma unroll
  for (int ks = 0; ks < 2; ++ks) {
    const int kc = (ks << 5) + ((lane >> 4) << 3);
    bf16x8 a[4], b[4];
#pragma unroll
    for (int i = 0; i < 4; ++i)
      a[i] = *(const bf16x8*)&Asm[(wid << 6) + (i << 4) + (lane & 15)][kc];
#pragma unroll
    for (int i = 0; i < 4; ++i)
      b[i] = *(const bf16x8*)&Bsm[(i << 4) + (lane & 15)][kc];
#pragma unroll
    for (int mf = 0; mf < 4; ++mf)
#pragma unroll
      for (int nf = 0; nf < 4; ++nf)
        acc[mf][nf] = __builtin_amdgcn_mfma_f32_16x16x32_bf16(a[mf], b[nf], acc[mf][nf], 0, 0, 0);
  }
}

// ---------------- conv1: 1x1, K=1024, out1[n][p][co] bf16, relu ----------------
__global__ __launch_bounds__(256) void conv1_k(
    const float* __restrict__ x, const u16* __restrict__ w1b,
    const float* __restrict__ b1, u16* __restrict__ out1) {
  __shared__ u16 Asm[256][72];
  __shared__ u16 Bsm[64][72];
  const int tid = threadIdx.x;
  const int lane = tid & 63, wid = tid >> 6;
  const int p0 = blockIdx.x * 64, n = blockIdx.z;

  const int ar0 = tid >> 2, ac = (tid & 3) << 4;   // A staging: row base, k-chunk
  const int bg = tid & 7;                          // B staging: pixel group
  const int bp = bg << 3;
  const int bk = (tid >> 3) << 1;                  // k pair

  const float* xb = x + (size_t)n * CIN * HWP + p0 + bp;
  const bool edge = (p0 + 64 > HWP);

  f32x4 acc[4][4] = {};

  for (int k0 = 0; k0 < CIN; k0 += 64) {
    // stage A: 256 rows x 64 k
#pragma unroll
    for (int q = 0; q < 4; ++q) {
      const u16* s = w1b + (size_t)(ar0 + (q << 6)) * CIN + k0 + ac;
      *(u16x8*)&Asm[ar0 + (q << 6)][ac] = *(const u16x8*)s;
      *(u16x8*)&Asm[ar0 + (q << 6)][ac + 8] = *(const u16x8*)(s + 8);
    }
    // stage B: transpose 2k x 8p, f32 -> bf16
    {
      const float* s0 = xb + (size_t)(k0 + bk) * HWP;
      const float* s1 = s0 + HWP;
      float va[8], vb[8];
      if (!edge) {
        f4 a0 = *(const f4*)s0, a1 = *(const f4*)(s0 + 4);
        f4 c0 = *(const f4*)s1, c1 = *(const f4*)(s1 + 4);
#pragma unroll
        for (int j = 0; j < 4; ++j) {
          va[j] = a0[j]; va[j + 4] = a1[j];
          vb[j] = c0[j]; vb[j + 4] = c1[j];
        }
      } else {
#pragma unroll
        for (int j = 0; j < 8; ++j) {
          const bool ok = (p0 + bp + j) < HWP;
          va[j] = ok ? s0[j] : 0.f;
          vb[j] = ok ? s1[j] : 0.f;
        }
      }
#pragma unroll
      for (int jj = 0; jj < 8; ++jj) {
        const int j = (jj + bg) & 7;  // rotate to spread LDS banks
        const uint32_t pk = (uint32_t)f2bf(va[j]) | ((uint32_t)f2bf(vb[j]) << 16);
        *(uint32_t*)&Bsm[bp + j][bk] = pk;
      }
    }
    __syncthreads();
    mfma_tile4(Asm, Bsm, acc, lane, wid);
    __syncthreads();
  }

#pragma unroll
  for (int mf = 0; mf < 4; ++mf) {
    const int cob = (wid << 6) + (mf << 4) + ((lane >> 4) << 2);
    const f4 bias = *(const f4*)(b1 + cob);
#pragma unroll
    for (int nf = 0; nf < 4; ++nf) {
      const int p = p0 + (nf << 4) + (lane & 15);
      if (p < HWP) {
        u16x4 pk;
#pragma unroll
        for (int v = 0; v < 4; ++v)
          pk[v] = f2bf(fmaxf(acc[mf][nf][v] + bias[v], 0.f));
        *(u16x4*)(out1 + (((size_t)(n * HWP + p)) << 8) + cob) = pk;
      }
    }
  }
}

// ---------------- conv2: 3x3 pad1, K=2304, out2[n][p][co] bf16, relu ----------------
__global__ __launch_bounds__(256) void conv2_k(
    const u16* __restrict__ o1, const u16* __restrict__ w2r,
    const float* __restrict__ b2, u16* __restrict__ o2) {
  __shared__ u16 Asm[256][72];
  __shared__ u16 Bsm[64][72];
  const int tid = threadIdx.x;
  const int lane = tid & 63, wid = tid >> 6;
  const int p0 = blockIdx.x * 64, n = blockIdx.z;

  const int ar0 = tid >> 2, ac = (tid & 3) << 4;
  const int p = p0 + ar0;                 // staging pixel for B
  const int hh = p / WID;
  const int wwp = p - hh * WID;

  f32x4 acc[4][4] = {};

  for (int kstep = 0; kstep < 36; ++kstep) {
    const int off = kstep >> 2;           // (dy,dx) index 0..8
    const int dy = off / 3 - 1;
    const int dx = off - (off / 3) * 3 - 1;
    // stage A
#pragma unroll
    for (int q = 0; q < 4; ++q) {
      const u16* s = w2r + (size_t)(ar0 + (q << 6)) * 2304 + kstep * 64 + ac;
      *(u16x8*)&Asm[ar0 + (q << 6)][ac] = *(const u16x8*)s;
      *(u16x8*)&Asm[ar0 + (q << 6)][ac + 8] = *(const u16x8*)(s + 8);
    }
    // stage B (zero-fill = padding semantics)
    {
      const int h2 = hh + dy, w2c = wwp + dx;
      const bool valid = (p < HWP) & ((unsigned)h2 < WID) & ((unsigned)w2c < WID);
      if (valid) {
        const u16* s = o1 + (((size_t)(n * HWP + h2 * WID + w2c)) << 8) + ((kstep & 3) << 6) + ac;
        *(u16x8*)&Bsm[ar0][ac] = *(const u16x8*)s;
        *(u16x8*)&Bsm[ar0][ac + 8] = *(const u16x8*)(s + 8);
      } else {
        const u16x8 z = {0, 0, 0, 0, 0, 0, 0, 0};
        *(u16x8*)&Bsm[ar0][ac] = z;
        *(u16x8*)&Bsm[ar0][ac + 8] = z;
      }
    }
    __syncthreads();
    mfma_tile4(Asm, Bsm, acc, lane, wid);
    __syncthreads();
  }

#pragma unroll
  for (int mf = 0; mf < 4; ++mf) {
    const int cob = (wid << 6) + (mf << 4) + ((lane >> 4) << 2);
    const f4 bias = *(const f4*)(b2 + cob);
#pragma unroll
    for (int nf = 0; nf < 4; ++nf) {
      const int pp = p0 + (nf << 4) + (lane & 15);
      if (pp < HWP) {
        u16x4 pk;
#pragma unroll
        for (int v = 0; v < 4; ++v)
          pk[v] = f2bf(fmaxf(acc[mf][nf][v] + bias[v], 0.f));
        *(u16x4*)(o2 + (((size_t)(n * HWP + pp)) << 8) + cob) = pk;
      }
    }
  }
}

// ---------------- conv3: 1x1, K=256, +bias +residual +relu, f32 NCHW out ----------------
__global__ __launch_bounds__(256) void conv3_k(
    const u16* __restrict__ o2, const u16* __restrict__ w3b,
    const float* __restrict__ b3, const float* __restrict__ x,
    float* __restrict__ out) {
  __shared__ u16 Asm[256][72];
  __shared__ u16 Bsm[64][72];
  const int tid = threadIdx.x;
  const int lane = tid & 63, wid = tid >> 6;
  const int p0 = blockIdx.x * 64, co0 = blockIdx.y << 8, n = blockIdx.z;

  const int ar0 = tid >> 2, ac = (tid & 3) << 4;
  const int p = p0 + ar0;
  const int pc = (p < HWP) ? p : 0;  // clamp; garbage columns never stored

  const u16* bb = o2 + (((size_t)(n * HWP + pc)) << 8) + ac;

  f32x4 acc[4][4] = {};

  for (int k0 = 0; k0 < CB; k0 += 64) {
#pragma unroll
    for (int q = 0; q < 4; ++q) {
      const u16* s = w3b + (size_t)(co0 + ar0 + (q << 6)) * CB + k0 + ac;
      *(u16x8*)&Asm[ar0 + (q << 6)][ac] = *(const u16x8*)s;
      *(u16x8*)&Asm[ar0 + (q << 6)][ac + 8] = *(const u16x8*)(s + 8);
    }
    *(u16x8*)&Bsm[ar0][ac] = *(const u16x8*)(bb + k0);
    *(u16x8*)&Bsm[ar0][ac + 8] = *(const u16x8*)(bb + k0 + 8);
    __syncthreads();
    mfma_tile4(Asm, Bsm, acc, lane, wid);
    __syncthreads();
  }

#pragma unroll
  for (int mf = 0; mf < 4; ++mf) {
    const int cob = co0 + (wid << 6) + (mf << 4) + ((lane >> 4) << 2);
    const f4 bias = *(const f4*)(b3 + cob);
#pragma unroll
    for (int nf = 0; nf < 4; ++nf) {
      const int pp = p0 + (nf << 4) + (lane & 15);
      if (pp < HWP) {
#pragma unroll
        for (int v = 0; v < 4; ++v) {
          const size_t idx = ((size_t)(n * COUT + cob + v)) * HWP + pp;
          out[idx] = fmaxf(acc[mf][nf][v] + bias[v] + x[idx], 0.f);
        }
      }
    }
  }
}

extern "C" void kernel_launch(void* const* d_in, const int* in_sizes, int n_in,
                              void* d_out, int out_size, void* d_ws, size_t ws_size,
                              hipStream_t stream) {
  const float* x  = (const float*)d_in[0];
  const float* w1 = (const float*)d_in[1];
  const float* w2 = (const float*)d_in[2];
  const float* w3 = (const float*)d_in[3];
  const float* s1 = (const float*)d_in[4];
  const float* b1 = (const float*)d_in[5];
  const float* s2 = (const float*)d_in[6];
  const float* b2 = (const float*)d_in[7];
  const float* s3 = (const float*)d_in[8];
  const float* b3 = (const float*)d_in[9];
  float* out = (float*)d_out;

  char* ws = (char*)d_ws;
  u16* w1b = (u16*)(ws);                       // 524288 B
  u16* w2r = (u16*)(ws + 524288);              // 1179648 B
  u16* w3b = (u16*)(ws + 1703936);             // 524288 B
  u16* o1  = (u16*)(ws + 2228224);             // 40960000 B
  u16* o2  = (u16*)(ws + 43188224);            // 40960000 B (total ~84.1 MB)

  prep_w<<<dim3(2304), dim3(256), 0, stream>>>(w1, w2, w3, s1, s2, s3, w1b, w2r, w3b);
  conv1_k<<<dim3(40, 1, 32), dim3(256), 0, stream>>>(x, w1b, b1, o1);
  conv2_k<<<dim3(40, 1, 32), dim3(256), 0, stream>>>(o1, w2r, b2, o2);
  conv3_k<<<dim3(40, 4, 32), dim3(256), 0, stream>>>(o2, w3b, b3, x, out);
}